// Round 11
// baseline (443.723 us; speedup 1.0000x reference)
//
#include <hip/hip_runtime.h>
#include <hip/hip_bf16.h>

typedef __attribute__((ext_vector_type(8))) short bf16x8;
typedef __attribute__((ext_vector_type(4))) float f32x4;
typedef __attribute__((ext_vector_type(8))) unsigned short u16x8;
typedef __attribute__((ext_vector_type(2))) unsigned short u16x2;

__device__ __forceinline__ unsigned short f2bf(float f) {
  union { float f; unsigned u; } c; c.f = f;
  unsigned u = c.u;
  u = (u + 0x7FFFu + ((u >> 16) & 1u)) >> 16;   // RNE
  return (unsigned short)u;
}

__device__ __forceinline__ void gld_lds16(const void* g, void* l) {
  __builtin_amdgcn_global_load_lds(
      (__attribute__((address_space(1))) unsigned int*)g,
      (__attribute__((address_space(3))) unsigned int*)l,
      16, 0, 0);
}

#define BAR() asm volatile("s_barrier" ::: "memory")

// ---------------- fused conversion kernel (R9 + lsum zero folded) ----------
__global__ void cvt_all(const float* __restrict__ x, unsigned short* __restrict__ x16,
                        const float* __restrict__ Kw, unsigned short* __restrict__ K16,
                        const float* __restrict__ V, unsigned short* __restrict__ Vt,
                        float* __restrict__ lsum) {
  const int b = blockIdx.x;
  const int tid = threadIdx.x;
  if (b < 32) lsum[b * 256 + tid] = 0.f;

  if (b < 6144) {
    const float* in;
    unsigned short* out;
    int i;
    if (b < 4096) {
      in = x; out = x16; i = (b * 256 + tid) * 8;
    } else {
      in = Kw; out = K16; i = ((b - 4096) * 256 + tid) * 8;
    }
    const float4* p = (const float4*)(in + i);
    float4 a = p[0], bb = p[1];
    u16x8 r;
    r[0] = f2bf(a.x); r[1] = f2bf(a.y); r[2] = f2bf(a.z); r[3] = f2bf(a.w);
    r[4] = f2bf(bb.x); r[5] = f2bf(bb.y); r[6] = f2bf(bb.z); r[7] = f2bf(bb.w);
    *(u16x8*)(out + i) = r;
  } else {
    __shared__ unsigned short t[64][66];
    const int tile = b - 6144;
    const int p0 = (tile & 63) * 64;
    const int e0 = (tile >> 6) * 64;
    const int cg = (tid & 15) * 4;
    const int pr = tid >> 4;
#pragma unroll
    for (int i = 0; i < 4; ++i) {
      int p = pr + i * 16;
      float4 v = *(const float4*)(V + (size_t)(p0 + p) * 1024 + e0 + cg);
      u16x2 lo, hi;
      lo[0] = f2bf(v.x); lo[1] = f2bf(v.y);
      hi[0] = f2bf(v.z); hi[1] = f2bf(v.w);
      *(u16x2*)&t[p][cg] = lo;
      *(u16x2*)&t[p][cg + 2] = hi;
    }
    __syncthreads();
    const int op = (tid & 7) * 8;
    const int oe = tid >> 3;
#pragma unroll
    for (int h = 0; h < 2; ++h) {
      int e = oe + h * 32;
      u16x8 r;
#pragma unroll
      for (int i = 0; i < 8; ++i) r[i] = t[op + i][e];
      *(u16x8*)(Vt + (size_t)(e0 + e) * 4096 + p0 + op) = r;
    }
  }
}

// ---- GEMM1 flat: A streamed global->regs, only B (K16) staged in LDS ------
// A [8192 x 1024], B [4096 x 1024] row-major bf16. 256x256 tile, 8 waves
// (2x4), per-wave 128x64. grid 512 (32m x 16n, XCD-swizzled).
// P = exp2(scale * A.B^T) -> Pout bf16 + row sums -> lsum (atomics).
//
// Per K-tile g (4 MFMA phases, only 2 barriers):
//  p0: 8 bF ds_reads | issue A-batch1(g+1) 8 glob loads | MFMA mi 0,1 | BAR
//  p1: stage B(g+2) (4 gld_lds) -> buf[g&1]            | MFMA mi 2,3
//  p2: issue A-batch2(g+1)                             | MFMA mi 4,5
//  p3:                                        MFMA mi 6,7 | vmcnt(12) | BAR
// vmcnt(12) drains B(g+1)+A1(g+1), leaves [B(g+2):4, A2(g+1):8]. Compiler
// auto-inserts counted waits for its own A register loads (RAW on VGPRs).
// WAR: p0-BAR separates bF reads of B(g) from p1's overwrite of buf[g&1].
__global__ __launch_bounds__(512, 2) void gemm_flat(
    const unsigned short* __restrict__ A, const unsigned short* __restrict__ B,
    unsigned short* __restrict__ Pout, float* __restrict__ lsum, float scale) {
  constexpr int NT = 16;                      // 1024 / 64

  __shared__ __align__(16) char lds[65536];   // 2 bufs x 2 B-units x 16KB

  const int tid = threadIdx.x;
  const int lane = tid & 63;
  const int w = tid >> 6;
  const int wm = w >> 2;        // 0..1
  const int wn = w & 3;         // 0..3
  const int q = lane >> 4;
  const int ml = lane & 15;

  const int bid = blockIdx.x;
  const int wg = (bid & 7) * 64 + (bid >> 3);
  const int row0 = (wg >> 4) * 256;
  const int col0 = (wg & 15) * 256;

  // B staging (chunk-XOR swizzle, R7-identical)
  const int cr = tid >> 3;
  const int ss = (tid & 7) ^ (cr & 7);
  char* ldsw = lds + w * 1024;
  auto stB = [&](int b, int t, int buf) {
    const unsigned short* s = B + (size_t)(col0 + b * 128 + cr) * 1024 + t * 64 + ss * 8;
    char* d = ldsw + (buf * 2 + b) * 16384;
    gld_lds16(s, d);
    gld_lds16(s + (size_t)64 * 1024, d + 8192);
  };

  const int ccB = (q ^ (ml & 7)) * 16;
  const int bOff = (wn >> 1) * 16384 + ((wn & 1) * 64 + ml) * 128 + ccB;

  // A stream base: row = row0 + wm*128 + mi*16 + ml ; k-chunk (ks*4+q)*8.
  const unsigned short* aB = A + (size_t)(row0 + wm * 128 + ml) * 1024 + q * 8;
  auto ldA = [&](int t, bf16x8 (&dst)[2][2][2], int half) {
    const unsigned short* s = aB + (size_t)half * 4 * 16 * 1024 + t * 64;
#pragma unroll
    for (int pp = 0; pp < 2; ++pp)
#pragma unroll
      for (int i = 0; i < 2; ++i)
#pragma unroll
        for (int ks = 0; ks < 2; ++ks)
          dst[pp][i][ks] =
              *(const bf16x8*)(s + (size_t)(pp * 2 + i) * 16 * 1024 + ks * 32);
  };

  f32x4 acc[8][4] = {};

  bf16x8 AA1[2][2][2], AA2[2][2][2], BB1[2][2][2], BB2[2][2][2];

  // Prologue: A(0) both halves to regs; B(0), B(1) staged. FIFO after:
  // [A1(0):8, B(0):4, A2(0):8, B(1):4]=24 -> vmcnt(12) drains A1(0)+B(0).
  ldA(0, AA1, 0);
  stB(0, 0, 0); stB(1, 0, 0);
  ldA(0, AA2, 1);
  stB(0, 1, 1); stB(1, 1, 1);
  asm volatile("s_waitcnt vmcnt(12)" ::: "memory");
  BAR();

  auto tile = [&](int g, bf16x8 (&aC1)[2][2][2], bf16x8 (&aC2)[2][2][2],
                  bf16x8 (&aN1)[2][2][2], bf16x8 (&aN2)[2][2][2]) {
    const char* base = lds + (g & 1) * 32768;
    const int tA = (g + 1) & (NT - 1);
    const int tB = (g + 2) & (NT - 1);

    bf16x8 bF[4][2];
#pragma unroll
    for (int ni = 0; ni < 4; ++ni)
#pragma unroll
      for (int ks = 0; ks < 2; ++ks)
        bF[ni][ks] = *(const bf16x8*)(base + (bOff ^ (ks * 64)) + ni * 2048);

    ldA(tA, aN1, 0);   // A-batch1(g+1)

    __builtin_amdgcn_s_setprio(1);
#pragma unroll
    for (int ks = 0; ks < 2; ++ks)
#pragma unroll
      for (int i = 0; i < 2; ++i)
#pragma unroll
        for (int ni = 0; ni < 4; ++ni)
          acc[i][ni] = __builtin_amdgcn_mfma_f32_16x16x32_bf16(
              aC1[0][i][ks], bF[ni][ks], acc[i][ni], 0, 0, 0);
    __builtin_amdgcn_s_setprio(0);
    BAR();   // all waves' bF reads of B(g) complete (consumed by MFMA above)

    stB(0, tB, g & 1);
    stB(1, tB, g & 1);
    __builtin_amdgcn_s_setprio(1);
#pragma unroll
    for (int ks = 0; ks < 2; ++ks)
#pragma unroll
      for (int i = 0; i < 2; ++i)
#pragma unroll
        for (int ni = 0; ni < 4; ++ni)
          acc[2 + i][ni] = __builtin_amdgcn_mfma_f32_16x16x32_bf16(
              aC1[1][i][ks], bF[ni][ks], acc[2 + i][ni], 0, 0, 0);
    __builtin_amdgcn_s_setprio(0);

    ldA(tA, aN2, 1);   // A-batch2(g+1)
    __builtin_amdgcn_s_setprio(1);
#pragma unroll
    for (int ks = 0; ks < 2; ++ks)
#pragma unroll
      for (int i = 0; i < 2; ++i)
#pragma unroll
        for (int ni = 0; ni < 4; ++ni)
          acc[4 + i][ni] = __builtin_amdgcn_mfma_f32_16x16x32_bf16(
              aC2[0][i][ks], bF[ni][ks], acc[4 + i][ni], 0, 0, 0);

#pragma unroll
    for (int ks = 0; ks < 2; ++ks)
#pragma unroll
      for (int i = 0; i < 2; ++i)
#pragma unroll
        for (int ni = 0; ni < 4; ++ni)
          acc[6 + i][ni] = __builtin_amdgcn_mfma_f32_16x16x32_bf16(
              aC2[1][i][ks], bF[ni][ks], acc[6 + i][ni], 0, 0, 0);
    __builtin_amdgcn_s_setprio(0);

    // Drain B(g+1) (+A1(g+1)); leave [B(g+2):4, A2(g+1):8] in flight.
    asm volatile("s_waitcnt vmcnt(12)" ::: "memory");
    BAR();
  };

  for (int gg = 0; gg < NT; gg += 2) {
    tile(gg, AA1, AA2, BB1, BB2);
    tile(gg + 1, BB1, BB2, AA1, AA2);
  }

#pragma unroll
  for (int mi = 0; mi < 8; ++mi) {
#pragma unroll
    for (int j = 0; j < 4; ++j) {
      const int gr = row0 + wm * 128 + mi * 16 + q * 4 + j;
      float rsum = 0.f;
#pragma unroll
      for (int ni = 0; ni < 4; ++ni) {
        const int gc = col0 + wn * 64 + ni * 16 + ml;
        float pv = exp2f(acc[mi][ni][j] * scale);  // scale includes log2(e)
        rsum += pv;
        Pout[(size_t)gr * 4096 + gc] = f2bf(pv);
      }
      rsum += __shfl_xor(rsum, 1);
      rsum += __shfl_xor(rsum, 2);
      rsum += __shfl_xor(rsum, 4);
      rsum += __shfl_xor(rsum, 8);
      if (ml == 0) atomicAdd(&lsum[gr], rsum);
    }
  }
}

// ---- GEMM2: R7-exact 8-phase (EPI1): BM=128,BN=256, grid 256 --------------
__global__ __launch_bounds__(512, 2) void gemm2(
    const unsigned short* __restrict__ A, const unsigned short* __restrict__ B,
    float* __restrict__ Cout, const float* __restrict__ lin) {
  constexpr int BM = 128, Kd = 4096, Nc = 1024, NT = 64;
  constexpr int AU = 1, NU = 3, M_rep = 4, PH = 2;

  __shared__ __align__(16) char lds[2 * NU * 16384];   // 96 KB

  const int tid = threadIdx.x;
  const int lane = tid & 63;
  const int w = tid >> 6;
  const int wm = w >> 2;
  const int wn = w & 3;
  const int q = lane >> 4;
  const int ml = lane & 15;

  const int bid = blockIdx.x;
  const int wg = (bid & 7) * 32 + (bid >> 3);
  const int row0 = (wg >> 2) * BM;
  const int col0 = (wg & 3) * 256;

  const int cr = tid >> 3;
  const int ss = (tid & 7) ^ (cr & 7);
  char* ldsw = lds + w * 1024;

  const int ccB = (q ^ (ml & 7)) * 16;
  const int aOff = (wm * 64 + ml) * 128 + ccB;
  const int bOff = (AU + (wn >> 1)) * 16384 + ((wn & 1) * 64 + ml) * 128 + ccB;

  f32x4 acc[M_rep][4] = {};

  auto stA = [&](int t, int buf) {
    const unsigned short* s = A + (size_t)(row0 + cr) * Kd + t * 64 + ss * 8;
    char* d = ldsw + (buf * NU) * 16384;
    gld_lds16(s, d);
    gld_lds16(s + (size_t)64 * Kd, d + 8192);
  };
  auto stB = [&](int b, int t, int buf) {
    const unsigned short* s = B + (size_t)(col0 + b * 128 + cr) * Kd + t * 64 + ss * 8;
    char* d = ldsw + (buf * NU + AU + b) * 16384;
    gld_lds16(s, d);
    gld_lds16(s + (size_t)64 * Kd, d + 8192);
  };

  stA(0, 0);
  stB(0, 0, 0); stB(1, 0, 0);
  stB(0, 1, 1); stB(1, 1, 1);
  asm volatile("s_waitcnt vmcnt(4)" ::: "memory");
  BAR();

  for (int g = 0; g < NT; ++g) {
    const char* base = lds + (g & 1) * (NU * 16384);
    const int tA = (g + 1) & (NT - 1);
    const int bufA = (g + 1) & 1;
    const int tB = (g + 2) & (NT - 1);
    const int bufB = g & 1;

    bf16x8 bF[4][2];
#pragma unroll
    for (int ni = 0; ni < 4; ++ni)
#pragma unroll
      for (int ks = 0; ks < 2; ++ks)
        bF[ni][ks] = *(const bf16x8*)(base + (bOff ^ (ks * 64)) + ni * 2048);

#pragma unroll
    for (int p = 0; p < PH; ++p) {
      bf16x8 aF[2][2];
#pragma unroll
      for (int i = 0; i < 2; ++i)
#pragma unroll
        for (int ks = 0; ks < 2; ++ks)
          aF[i][ks] = *(const bf16x8*)(base + ((aOff ^ (ks * 64)) + (2 * p + i) * 2048));

      if (p == 0) stA(tA, bufA);
      else { stB(0, tB, bufB); stB(1, tB, bufB); }

      BAR();
      __builtin_amdgcn_s_setprio(1);
#pragma unroll
      for (int ks = 0; ks < 2; ++ks)
#pragma unroll
        for (int i = 0; i < 2; ++i)
#pragma unroll
          for (int ni = 0; ni < 4; ++ni)
            acc[2 * p + i][ni] = __builtin_amdgcn_mfma_f32_16x16x32_bf16(
                aF[i][ks], bF[ni][ks], acc[2 * p + i][ni], 0, 0, 0);
      __builtin_amdgcn_s_setprio(0);
      if (p == PH - 1) asm volatile("s_waitcnt vmcnt(4)" ::: "memory");
      BAR();
    }
  }

#pragma unroll
  for (int mi = 0; mi < M_rep; ++mi) {
#pragma unroll
    for (int j = 0; j < 4; ++j) {
      const int gr = row0 + wm * (BM / 2) + mi * 16 + q * 4 + j;
      const float rl = 1.0f / lin[gr];
#pragma unroll
      for (int ni = 0; ni < 4; ++ni) {
        const int gc = col0 + wn * 64 + ni * 16 + ml;
        Cout[(size_t)gr * Nc + gc] = acc[mi][ni][j] * rl;
      }
    }
  }
}

extern "C" void kernel_launch(void* const* d_in, const int* in_sizes, int n_in,
                              void* d_out, int out_size, void* d_ws,
                              size_t ws_size, hipStream_t stream) {
  const float* x = (const float*)d_in[0];   // [8192,1024]
  const float* Kw = (const float*)d_in[1];  // [4096,1024]
  const float* Vw = (const float*)d_in[2];  // [4096,1024]
  float* out = (float*)d_out;               // [8192,1024]
  char* ws = (char*)d_ws;

  unsigned short* x16  = (unsigned short*)(ws);                   // 16 MB
  unsigned short* K16  = (unsigned short*)(ws + (16u << 20));     //  8 MB
  unsigned short* V16t = (unsigned short*)(ws + (24u << 20));     //  8 MB
  float*          lsum = (float*)(ws + (32u << 20));              // 32 KB
  unsigned short* P16  = (unsigned short*)(ws + (33u << 20));     // 64 MB

  cvt_all<<<7168, 256, 0, stream>>>(x, x16, Kw, K16, Vw, V16t, lsum);

  // GEMM1 (flat-A): P = exp(x16 . K16^T / 32), row sums -> lsum.
  gemm_flat<<<512, 512, 0, stream>>>(
      x16, K16, P16, lsum, 0.03125f * 1.44269504088896340736f);
  // GEMM2: out = (P16 . V16t^T) / lsum[row]
  gemm2<<<256, 512, 0, stream>>>(P16, V16t, out, lsum);
}